// Round 1
// baseline (1759.093 us; speedup 1.0000x reference)
//
#include <hip/hip_runtime.h>
#include <math.h>

// Gated DeltaNet chunkwise recurrence on MFMA (gfx950).
// V2: two workgroups per CU. grid = 32 heads x 16 v-slices (16 cols each);
// 512 thr = 8 waves per WG; LDS trimmed to 81536 B (<= 80 KiB) so 2 WGs
// co-reside per CU and overlap each other's barrier/solve/load stalls.
// Operands stored UNGATED (kn = k/||k||, qn = scale*q/||q||); the decay
// gates e^{gc_j} * e^{-gc_i} are applied in fp32 epilogues:
//   A    [i][j] = beta_i * gexp_j * ginv_i * (kn_i . kn_j)   (j<i)
//   Aqk2 [i][j] =          ginv_i * (qn_i . kn_j)            (j<=i)
//   Y[i]  = gexp_i * (V[i] - kn_i.S)
//   corg  = gexp_i * (T.Y)        (gexp-scaled cor; feeds both PO and PSU)
//   O[i]  = gexp_i * (qn_i.S) + Aqk2 . corg
//   S'    = decay * S + kn^T . corg
// LDS aliasing: Vinv lives in sA's unused upper-right; gate vectors live in
// sA rows 0-15 cols 16-31 (never touched by the solve); sTmp and sYT share
// one union buffer (lifetimes separated by barriers b8/b9).

namespace {

constexpr int kBH = 32;
constexpr int kS = 4096;
constexpr int kDk = 128;
constexpr int kDv = 256;
constexpr int kL = 64;
constexpr int kNC = kS / kL;
constexpr int kThreads = 512;
constexpr int kVSlices = 16;    // 16 cols per WG
constexpr float kScale = 0.08838834764831845f;  // 128^-0.5
constexpr float kEps = 1e-6f;

constexpr int KST = 136;  // bf16 row stride, 128-col mats (16B-aligned rows)
constexpr int TST = 72;   // bf16 row stride, 64-col mats
constexpr int SBT = 136;  // bf16 row stride for S^T snapshot
constexpr int AS  = 68;   // fp32 row stride for A / solve

typedef __attribute__((ext_vector_type(8))) short short8;
typedef __attribute__((ext_vector_type(4))) short short4v;
typedef __attribute__((ext_vector_type(4))) float f32x4;

__device__ __forceinline__ short f2bf(float f) {
  union { float f; unsigned u; } x;
  x.f = f;
  unsigned r = x.u + 0x7fffu + ((x.u >> 16) & 1u);  // RNE
  return (short)(r >> 16);
}

#define MFMA16(a, b, c) __builtin_amdgcn_mfma_f32_16x16x32_bf16((a), (b), (c), 0, 0, 0)

__global__ __launch_bounds__(kThreads, 4)
void gdn_mfma_kernel(const float* __restrict__ q, const float* __restrict__ k,
                     const float* __restrict__ v, const float* __restrict__ g,
                     const float* __restrict__ beta, float* __restrict__ out) {
  __shared__ __align__(16) short sKn[kL][KST];   // k/||k||            17408 B
  __shared__ __align__(16) short sQn[kL][KST];   // scale*q/||q||      17408 B
  __shared__ __align__(16) short sTb[kL][TST];   // T bf16 (upper 0)    9216 B
  __shared__ __align__(16) short sAqk[kL][TST];  // ginv_i-scaled qk    9216 B
  __shared__ __align__(16) short sSb[16][SBT];   // S^T snapshot bf16   4352 B
  __shared__ __align__(16) float sA[kL][AS];     // A + Vinv + gates   17408 B
  __shared__ __align__(16) float sU[1056];       // sTmp | sYT union    4224 B
  __shared__ __align__(16) short sCG[16][TST];   // gexp-scaled cor^T   2304 B
  // total 81536 B -> 2 WGs/CU

  // gate vectors aliased into sA rows 0..15, cols 16..31 (never written by
  // PA's strictly-lower writes nor by the solve; Vinv uses cols 32..65).
#define GEXPV(i) sA[(i) >> 4][16 + ((i) & 15)]
#define GINVV(i) sA[4 + ((i) >> 4)][16 + ((i) & 15)]
#define BETAV(i) sA[8 + ((i) >> 4)][16 + ((i) & 15)]
  // Vinv blocks aliased into sA rows 0..31, cols 32..65 (upper triangle).
#define SVINV(I, i, c) sA[((I) & 1) * 16 + (i)][32 + ((I) >> 1) * 17 + (c)]
#define STMP(r, c) sU[(r) * 33 + (c)]
  short* const sYT = (short*)sU;  // [16][TST] bf16 view, alias of sTmp

  const int t = threadIdx.x;
  const int wave = t >> 6;
  const int lane = t & 63;
  const int n16 = lane & 15;
  const int quad = lane >> 4;
  const int r2 = t >> 3;  // 0..63 staging row
  const int c8 = t & 7;   // 16-col group within row

  const int bh = blockIdx.x & 31;   // all 16 slices of a head share an XCD
  const int vb = blockIdx.x >> 5;   // 0..15

  const float* qp_g = q + (size_t)bh * kS * kDk;
  const float* kp_g = k + (size_t)bh * kS * kDk;
  const float* vp_g = v + (size_t)bh * kS * kDv + vb * 16;
  const float* gp_g = g + (size_t)bh * kS;
  const float* bp_g = beta + (size_t)bh * kS;
  float* op_g = out + (size_t)bh * kS * kDv + vb * 16;
  float* sp_g = out + (size_t)kBH * kS * kDv + (size_t)bh * kDk * kDv + vb * 16;

  // persistent-zero regions (upper triangles never rewritten) + S^T snapshot
  for (int i = t; i < kL * TST; i += kThreads) { (&sTb[0][0])[i] = 0; (&sAqk[0][0])[i] = 0; }
  for (int i = t; i < 16 * SBT; i += kThreads) (&sSb[0][0])[i] = 0;

  f32x4 Sacc[2];  // waves 0-3: state tiles d0 = wave*32 + a*16, v = n16
  Sacc[0] = 0; Sacc[1] = 0;

  const int iy0 = (wave & 3) * 16;  // i-tile for this wave (both wave groups)

  for (int n = 0; n < kNC; ++n) {
    __syncthreads();  // b0: previous chunk fully consumed

    // ---- stage1: global loads + norms (regs); wave0: gates ----
    float kv[16], qv[16], rk, rq;
    {
      const float* krow = kp_g + (size_t)(n * kL + r2) * kDk + c8 * 16;
      const float* qrow = qp_g + (size_t)(n * kL + r2) * kDk + c8 * 16;
      float ssk = 0.f, ssq = 0.f;
      #pragma unroll
      for (int m = 0; m < 4; ++m) {
        const float4 a = reinterpret_cast<const float4*>(krow)[m];
        const float4 b = reinterpret_cast<const float4*>(qrow)[m];
        kv[4*m+0]=a.x; kv[4*m+1]=a.y; kv[4*m+2]=a.z; kv[4*m+3]=a.w;
        qv[4*m+0]=b.x; qv[4*m+1]=b.y; qv[4*m+2]=b.z; qv[4*m+3]=b.w;
        ssk += a.x*a.x + a.y*a.y + a.z*a.z + a.w*a.w;
        ssq += b.x*b.x + b.y*b.y + b.z*b.z + b.w*b.w;
      }
      #pragma unroll
      for (int off = 4; off >= 1; off >>= 1) {
        ssk += __shfl_xor(ssk, off, 8);
        ssq += __shfl_xor(ssq, off, 8);
      }
      rk = 1.f / (sqrtf(ssk) + kEps);
      rq = 1.f / (sqrtf(ssq) + kEps);
    }
    if (t < kL) {
      float gv = gp_g[n * kL + t];
      float bt = bp_g[n * kL + t];
      #pragma unroll
      for (int off = 1; off < 64; off <<= 1) {
        float up = __shfl_up(gv, off, 64);
        if (lane >= off) gv += up;
      }
      GEXPV(t) = __expf(gv);
      GINVV(t) = __expf(-gv);
      BETAV(t) = bt;
    }
    // ---- stage2: write the two ungated bf16 operand matrices (no barrier
    //      needed between stage1/stage2: only own-thread regs used) ----
    {
      const float mk = rk, mq = rq * kScale;
      short8 w0, w1;
      #pragma unroll
      for (int m = 0; m < 8; ++m) { w0[m] = f2bf(kv[m] * mk); w1[m] = f2bf(kv[8+m] * mk); }
      *(short8*)&sKn[r2][c8*16] = w0; *(short8*)&sKn[r2][c8*16+8] = w1;
      #pragma unroll
      for (int m = 0; m < 8; ++m) { w0[m] = f2bf(qv[m] * mq); w1[m] = f2bf(qv[8+m] * mq); }
      *(short8*)&sQn[r2][c8*16] = w0; *(short8*)&sQn[r2][c8*16+8] = w1;
    }
    __syncthreads();  // b2: operands + gates visible

    // ---- PA: KK (waves 0-3 -> strictly-lower A) / QK (waves 4-7 -> Aqk) ----
    float vv[4];
    {
      const int jmax = wave & 3;
      const short (*Asrc)[KST] = (wave < 4) ? sKn : sQn;
      f32x4 acc[4];
      acc[0] = 0; acc[1] = 0; acc[2] = 0; acc[3] = 0;
      if (wave >= 4) {  // issue v loads early; consumed at the Y epilogue
        #pragma unroll
        for (int reg = 0; reg < 4; ++reg)
          vv[reg] = vp_g[(size_t)(n*kL + iy0 + quad*4 + reg) * kDv + n16];
      }
      #pragma unroll
      for (int ks = 0; ks < 4; ++ks) {
        short8 af = *(const short8*)&Asrc[iy0 + n16][ks*32 + quad*8];
        for (int jt = 0; jt <= jmax; ++jt) {
          short8 bf = *(const short8*)&sKn[jt*16 + n16][ks*32 + quad*8];
          acc[jt] = MFMA16(af, bf, acc[jt]);
        }
      }
      if (wave < 4) {
        float sc[4];
        #pragma unroll
        for (int reg = 0; reg < 4; ++reg) {
          const int i = iy0 + quad*4 + reg;
          sc[reg] = BETAV(i) * GINVV(i);
        }
        for (int jt = 0; jt <= jmax; ++jt) {
          const int j = jt*16 + n16;
          const float gej = GEXPV(j);
          #pragma unroll
          for (int reg = 0; reg < 4; ++reg) {
            const int i = iy0 + quad*4 + reg;
            if (j < i) sA[i][j] = sc[reg] * gej * acc[jt][reg];
          }
        }
      } else {
        float gi[4];
        #pragma unroll
        for (int reg = 0; reg < 4; ++reg) gi[reg] = GINVV(iy0 + quad*4 + reg);
        for (int jt = 0; jt <= jmax; ++jt) {
          #pragma unroll
          for (int reg = 0; reg < 4; ++reg) {
            const int i = iy0 + quad*4 + reg, j = jt*16 + n16;
            sAqk[i][j] = (j <= i) ? f2bf(acc[jt][reg] * gi[reg]) : (short)0;
          }
        }
      }
    }
    __syncthreads();  // b3

    // ---- interleaved: solve (waves 0-3, fp32) || PY = [kn;qn].S (waves 4-7) ----
    f32x4 yacc = 0, oacc = 0;
    auto py_step = [&](int ks) {
      short8 ak = *(const short8*)&sKn[iy0 + n16][ks*32 + quad*8];
      short8 aq = *(const short8*)&sQn[iy0 + n16][ks*32 + quad*8];
      short8 bs = *(const short8*)&sSb[n16][ks*32 + quad*8];
      yacc = MFMA16(ak, bs, yacc);
      oacc = MFMA16(aq, bs, oacc);
    };

    if (wave >= 4) {
      py_step(0);
    } else if (t < 64) {
      // S1: invert the four 16x16 unit-lower diagonal blocks
      const int I = t >> 4, c = t & 15;
      float x[16];
      #pragma unroll
      for (int i = 0; i < 16; ++i) {
        float xi = (i == c) ? 1.f : 0.f;
        for (int j = 0; j < i; ++j) xi -= sA[I*16 + i][I*16 + j] * x[j];
        x[i] = xi;
      }
      const float bc = BETAV(I*16 + c);
      #pragma unroll
      for (int i = 0; i < 16; ++i) {
        SVINV(I, i, c) = x[i];
        sTb[I*16 + i][I*16 + c] = f2bf(x[i] * bc);
      }
    }
    __syncthreads();  // b4

    if (wave >= 4) {
      py_step(1);
    } else {
      // S2a: M10 = V1*A10, M32 = V3*A32   (t < 256)
      const int r = t >> 4, c = t & 15;
      float m1 = 0.f, m3 = 0.f;
      #pragma unroll
      for (int kk = 0; kk < 16; ++kk) {
        m1 += SVINV(1, r, kk) * sA[16 + kk][c];
        m3 += SVINV(3, r, kk) * sA[48 + kk][32 + c];
      }
      STMP(r, c) = m1;
      STMP(16 + r, c) = m3;
    }
    __syncthreads();  // b5

    if (wave >= 4) {
      py_step(2);
    } else {
      // S2b: X10 = -M10*V0 ; X32 = -M32*V2
      const int r = t >> 4, c = t & 15;
      float x1 = 0.f, x3 = 0.f;
      #pragma unroll
      for (int kk = 0; kk < 16; ++kk) {
        x1 += STMP(r, kk) * SVINV(0, kk, c);
        x3 += STMP(16 + r, kk) * SVINV(2, kk, c);
      }
      x1 = -x1; x3 = -x3;
      sA[16 + r][c] = x1;
      sTb[16 + r][c] = f2bf(x1 * BETAV(c));
      sA[48 + r][32 + c] = x3;
      sTb[48 + r][32 + c] = f2bf(x3 * BETAV(32 + c));
    }
    __syncthreads();  // b6

    if (wave >= 4) {
      py_step(3);
    } else {
      // S3a: M = A_bl * W1inv  (32x32), W1inv = [[V0,0],[X10,V1]]
      #pragma unroll
      for (int p = 0; p < 4; ++p) {
        const int idx = t + 256*p;
        const int r = idx >> 5, c = idx & 31;
        float m = 0.f;
        if (c < 16) {
          #pragma unroll
          for (int kk = 0; kk < 16; ++kk) m += sA[32 + r][kk] * SVINV(0, kk, c);
          #pragma unroll
          for (int kk = 16; kk < 32; ++kk) m += sA[32 + r][kk] * sA[kk][c];
        } else {
          #pragma unroll
          for (int kk = 16; kk < 32; ++kk) m += sA[32 + r][kk] * SVINV(1, kk - 16, c - 16);
        }
        STMP(r, c) = m;
      }
    }
    __syncthreads();  // b7

    // R5: waves 0-3: S3b (last sTmp reader) ; waves 4-7: Y values + PO prep
    short4v yw;
    short8 af2[2];
    if (wave >= 4) {
      #pragma unroll
      for (int reg = 0; reg < 4; ++reg) {
        const float ge = GEXPV(iy0 + quad*4 + reg);
        yw[reg] = f2bf(ge * (vv[reg] - yacc[reg]));  // Y = gexp*(V - kn.S)
        oacc[reg] *= ge;                             // O_inter = gexp*(qn.S)
      }
      af2[0] = *(const short8*)&sAqk[iy0 + n16][quad*8];
      af2[1] = *(const short8*)&sAqk[iy0 + n16][32 + quad*8];
    } else {
      // S3b: X_bl = -W2inv * M, W2inv = [[V2,0],[X32,V3]]
      #pragma unroll
      for (int p = 0; p < 4; ++p) {
        const int idx = t + 256*p;
        const int r = idx >> 5, c = idx & 31;
        float xv = 0.f;
        if (r < 16) {
          #pragma unroll
          for (int kk = 0; kk < 16; ++kk) xv += SVINV(2, r, kk) * STMP(kk, c);
        } else {
          #pragma unroll
          for (int kk = 0; kk < 16; ++kk) xv += sA[32 + r][32 + kk] * STMP(kk, c);
          #pragma unroll
          for (int kk = 16; kk < 32; ++kk) xv += SVINV(3, r - 16, kk - 16) * STMP(kk, c);
        }
        sTb[32 + r][c] = f2bf(-xv * BETAV(c));
      }
    }
    __syncthreads();  // b8: sTmp dead -> sYT (union) may be written

    // R6: waves 4-7 store Y^T ; waves 0-3 prefetch kn^T fragments for PSU
    short8 afr[2][2];
    if (wave >= 4) {
      *(short4v*)&sYT[n16*TST + iy0 + quad*4] = yw;
    } else {
      const int d0b = (wave & 3) * 32;
      #pragma unroll
      for (int a = 0; a < 2; ++a)
        #pragma unroll
        for (int ks = 0; ks < 2; ++ks) {
          short8 af;
          #pragma unroll
          for (int j = 0; j < 8; ++j)
            af[j] = sKn[ks*32 + quad*8 + j][d0b + a*16 + n16];
          afr[a][ks] = af;
        }
    }
    __syncthreads();  // b9

    // R7: PC (waves 0-3): corg^T = gexp_i * (T.Y)^T -> sCG
    if (wave < 4) {
      f32x4 cacc = 0;
      #pragma unroll
      for (int ks = 0; ks < 2; ++ks) {
        short8 af = *(const short8*)&sTb[iy0 + n16][ks*32 + quad*8];
        short8 bf = *(const short8*)&sYT[n16*TST + ks*32 + quad*8];
        cacc = MFMA16(af, bf, cacc);
      }
      short4v cw;
      #pragma unroll
      for (int reg = 0; reg < 4; ++reg)
        cw[reg] = f2bf(cacc[reg] * GEXPV(iy0 + quad*4 + reg));
      *(short4v*)&sCG[n16][iy0 + quad*4] = cw;
    }
    __syncthreads();  // b10

    // R8: PO (waves 4-7): O = gexp*qn.S + Aqk2.corg -> global
    //     PSU (waves 0-3): S = decay*S + kn^T.corg (in accumulators)
    if (wave >= 4) {
      #pragma unroll
      for (int ks = 0; ks < 2; ++ks) {
        short8 bf = *(const short8*)&sCG[n16][ks*32 + quad*8];
        oacc = MFMA16(af2[ks], bf, oacc);
      }
      #pragma unroll
      for (int reg = 0; reg < 4; ++reg)
        op_g[(size_t)(n*kL + iy0 + quad*4 + reg) * kDv + n16] = oacc[reg];
    } else {
      const float decay = GEXPV(kL - 1);
      Sacc[0] *= decay; Sacc[1] *= decay;
      #pragma unroll
      for (int a = 0; a < 2; ++a) {
        #pragma unroll
        for (int ks = 0; ks < 2; ++ks) {
          short8 bf = *(const short8*)&sCG[n16][ks*32 + quad*8];
          Sacc[a] = MFMA16(afr[a][ks], bf, Sacc[a]);
        }
        short4v sw;
        #pragma unroll
        for (int reg = 0; reg < 4; ++reg) sw[reg] = f2bf(Sacc[a][reg]);
        *(short4v*)&sSb[n16][(wave & 3)*32 + a*16 + quad*4] = sw;
      }
    }
  }

  // ---- final state (fp32 from accumulators) -> d_out tail ----
  if (wave < 4) {
    #pragma unroll
    for (int a = 0; a < 2; ++a)
      #pragma unroll
      for (int reg = 0; reg < 4; ++reg) {
        const int d = (wave & 3)*32 + a*16 + quad*4 + reg;
        sp_g[(size_t)d * kDv + n16] = Sacc[a][reg];
      }
  }
#undef GEXPV
#undef GINVV
#undef BETAV
#undef SVINV
#undef STMP
}

}  // namespace

extern "C" void kernel_launch(void* const* d_in, const int* in_sizes, int n_in,
                              void* d_out, int out_size, void* d_ws, size_t ws_size,
                              hipStream_t stream) {
  (void)in_sizes; (void)n_in; (void)d_ws; (void)ws_size; (void)out_size;
  const float* q    = (const float*)d_in[0];
  const float* k    = (const float*)d_in[1];
  const float* v    = (const float*)d_in[2];
  const float* g    = (const float*)d_in[3];
  const float* beta = (const float*)d_in[4];
  float* out = (float*)d_out;
  gdn_mfma_kernel<<<dim3(kBH * kVSlices), dim3(kThreads), 0, stream>>>(
      q, k, v, g, beta, out);
}

// Round 2
// 1300.266 us; speedup vs baseline: 1.3529x; 1.3529x over previous
//
#include <hip/hip_runtime.h>
#include <math.h>

// Gated DeltaNet chunkwise recurrence on MFMA (gfx950).
// V3: cross-chunk software pipeline with wave specialization.
// grid = 32 heads x 8 v-slices (32 cols, V1's proven memory layout); 512 thr.
// Waves 0-3 ("A") run chunk n's S-dependent chain (PY -> Y -> cor -> O, S-update,
// Sacc lives in their accumulators). Waves 4-7 ("B") concurrently prep chunk n+1:
// global staging + norms + gates + KK/QK MFMA + the 5-stage 64x64 unit-lower
// solve. Operand/T/Aqk LDS double-buffered; 7 barriers/iter, every interval
// pairs A-MFMA with B-VALU so the pipes overlap. All global prefetch is issued
// at the start of the S1 interval (longest serial stage) to hide the vmcnt
// drain at the following barrier.
// Algebra (identical to verified V2): operands stored UNGATED
// (kn = k/||k||, qn = scale*q/||q||), decay gates applied in fp32 epilogues:
//   A[i][j]    = beta_i * ginv_i * gexp_j * (kn_i.kn_j)   (j<i)
//   Aqk2[i][j] = ginv_i * (qn_i.kn_j)                     (j<=i)
//   Y[i]  = gexp_i * (V[i] - kn_i.S)
//   corg  = gexp_i * (T.Y)
//   O[i]  = gexp_i * (qn_i.S) + Aqk2.corg
//   S'    = decay * S + kn^T.corg

namespace {

constexpr int kBH = 32;
constexpr int kS = 4096;
constexpr int kDk = 128;
constexpr int kDv = 256;
constexpr int kL = 64;
constexpr int kNC = kS / kL;     // 64 chunks
constexpr int kThreads = 512;
constexpr float kScale = 0.08838834764831845f;  // 128^-0.5
constexpr float kEps = 1e-6f;

constexpr int KST = 136;  // bf16 row stride, 128-col mats
constexpr int TST = 72;   // bf16 row stride, 64-col mats
constexpr int SBT = 136;  // bf16 row stride for S^T snapshot
constexpr int AS  = 68;   // fp32 row stride for A / solve

typedef __attribute__((ext_vector_type(8))) short short8;
typedef __attribute__((ext_vector_type(4))) short short4v;
typedef __attribute__((ext_vector_type(4))) float f32x4;

__device__ __forceinline__ short f2bf(float f) {
  union { float f; unsigned u; } x;
  x.f = f;
  unsigned r = x.u + 0x7fffu + ((x.u >> 16) & 1u);  // RNE
  return (short)(r >> 16);
}

#define MFMA16(a, b, c) __builtin_amdgcn_mfma_f32_16x16x32_bf16((a), (b), (c), 0, 0, 0)

__global__ __launch_bounds__(kThreads, 2)
void gdn_mfma_kernel(const float* __restrict__ q, const float* __restrict__ k,
                     const float* __restrict__ v, const float* __restrict__ g,
                     const float* __restrict__ beta, float* __restrict__ out) {
  // double-buffered operand / T / Aqk LDS (buffer = chunk & 1)
  __shared__ __align__(16) short sKn[2][kL][KST];   // 34816 B
  __shared__ __align__(16) short sQn[2][kL][KST];   // 34816 B
  __shared__ __align__(16) short sTb[2][kL][TST];   // 18432 B (upper tiles stay 0)
  __shared__ __align__(16) short sAqk[2][kL][TST];  // 18432 B (upper tiles stay 0)
  __shared__ __align__(16) short sSb[32][SBT];      //  8704 B  S^T snapshot bf16
  __shared__ __align__(16) float sA[kL][AS];        // 17408 B  A + Vinv (B-only)
  __shared__ __align__(16) float sU[1152];          //  4608 B  sTmp | sYT union
  __shared__ __align__(16) short sCG[32][TST];      //  4608 B  gexp-scaled cor^T
  __shared__ __align__(16) float sGe[2][kL];        //   512 B  exp(+gcum) dbuf
  __shared__ __align__(16) float sGi[kL];           //   256 B  exp(-gcum)
  __shared__ __align__(16) float sBeta[kL];         //   256 B
  // total 142848 B -> 1 WG/CU (intended; pipeline supplies the overlap)

  // Vinv blocks aliased into sA rows 0..31, cols 32..65 (above the strict-lower A).
#define SVINV(I, i, c) sA[((I) & 1) * 16 + (i)][32 + ((I) >> 1) * 17 + (c)]
#define STMP(r, c) sU[(r) * 33 + (c)]
  short* const sYT = (short*)sU;  // [32][TST] bf16 view (lifetime-disjoint with sTmp)

  const int t = threadIdx.x;
  const int wave = t >> 6;
  const int lane = t & 63;
  const int n16 = lane & 15;
  const int quad = lane >> 4;
  const bool isA = (t < 256);     // waves 0-3: S-chain.  waves 4-7: prep.
  const int t2 = t & 255;         // B-group local index (0..255)
  const int wb = wave - 4;        // B wave id (valid for !isA)
  const int wa = wave & 3;
  const int iy0 = wa * 16;        // i-tile for A-group phases

  const int r2b = t2 >> 2;        // B staging row 0..63
  const int cb32 = (t2 & 3) * 32; // B staging col base (floats)

  const int bh = blockIdx.x & 31;
  const int vb = blockIdx.x >> 5; // 0..7, 32-col slices

  const float* qp_g = q + (size_t)bh * kS * kDk;
  const float* kp_g = k + (size_t)bh * kS * kDk;
  const float* vp_g = v + (size_t)bh * kS * kDv + vb * 32;
  const float* gp_g = g + (size_t)bh * kS;
  const float* bp_g = beta + (size_t)bh * kS;
  float* op_g = out + (size_t)bh * kS * kDv + vb * 32;
  float* sp_g = out + (size_t)kBH * kS * kDv + (size_t)bh * kDk * kDv + vb * 32;

  // persistent-zero regions (upper triangles never rewritten) + S^T snapshot
  for (int i = t; i < 2 * kL * TST; i += kThreads) {
    (&sTb[0][0][0])[i] = 0;
    (&sAqk[0][0][0])[i] = 0;
  }
  for (int i = t; i < 32 * SBT; i += kThreads) (&sSb[0][0])[i] = 0;

  f32x4 Sacc[4];  // A-waves: state tiles d0 = wa*32 + a*16, v = b*16 + n16
  Sacc[0] = 0; Sacc[1] = 0; Sacc[2] = 0; Sacc[3] = 0;
  f32x4 yacc[2], oacc[2];
  float vv[2][4];
  float4 kv4[8], qv4[8];
  float gv0 = 0.f, bt0 = 0.f;

  // ---- B prologue: load chunk 0 q/k (+ gates on wave 4) ----
  if (!isA) {
    const float* krow = kp_g + (size_t)r2b * kDk + cb32;
    const float* qrow = qp_g + (size_t)r2b * kDk + cb32;
    #pragma unroll
    for (int m = 0; m < 8; ++m) {
      kv4[m] = reinterpret_cast<const float4*>(krow)[m];
      qv4[m] = reinterpret_cast<const float4*>(qrow)[m];
    }
    if (wb == 0) { gv0 = gp_g[lane]; bt0 = bp_g[lane]; }
  }

  for (int it = 0; it <= kNC; ++it) {
    const int cbuf = it & 1;        // B stages chunk `it` here
    const int pbuf = cbuf ^ 1;      // A consumes chunk `it-1` from here
    const bool doA = (it > 0);
    const bool doB = (it < kNC);

    // ============ int0: B: gates+norms+stage2 | A: PY + Y epilogue ============
    if (doB) {
      if (wave == 4) {
        float gv = gv0;
        #pragma unroll
        for (int off = 1; off < 64; off <<= 1) {
          float up = __shfl_up(gv, off, 64);
          if (lane >= off) gv += up;
        }
        sGe[cbuf][lane] = __expf(gv);
        sGi[lane] = __expf(-gv);
        sBeta[lane] = bt0;
      }
      if (!isA) {
        float ssk = 0.f, ssq = 0.f;
        #pragma unroll
        for (int m = 0; m < 8; ++m) {
          ssk += kv4[m].x * kv4[m].x + kv4[m].y * kv4[m].y +
                 kv4[m].z * kv4[m].z + kv4[m].w * kv4[m].w;
          ssq += qv4[m].x * qv4[m].x + qv4[m].y * qv4[m].y +
                 qv4[m].z * qv4[m].z + qv4[m].w * qv4[m].w;
        }
        ssk += __shfl_xor(ssk, 1, 4); ssk += __shfl_xor(ssk, 2, 4);
        ssq += __shfl_xor(ssq, 1, 4); ssq += __shfl_xor(ssq, 2, 4);
        const float mk = 1.f / (sqrtf(ssk) + kEps);
        const float mq = kScale / (sqrtf(ssq) + kEps);
        #pragma unroll
        for (int m = 0; m < 4; ++m) {
          const float4 a = kv4[2 * m], b2 = kv4[2 * m + 1];
          short8 w;
          w[0] = f2bf(a.x * mk);  w[1] = f2bf(a.y * mk);
          w[2] = f2bf(a.z * mk);  w[3] = f2bf(a.w * mk);
          w[4] = f2bf(b2.x * mk); w[5] = f2bf(b2.y * mk);
          w[6] = f2bf(b2.z * mk); w[7] = f2bf(b2.w * mk);
          *(short8*)&sKn[cbuf][r2b][cb32 + m * 8] = w;
        }
        #pragma unroll
        for (int m = 0; m < 4; ++m) {
          const float4 a = qv4[2 * m], b2 = qv4[2 * m + 1];
          short8 w;
          w[0] = f2bf(a.x * mq);  w[1] = f2bf(a.y * mq);
          w[2] = f2bf(a.z * mq);  w[3] = f2bf(a.w * mq);
          w[4] = f2bf(b2.x * mq); w[5] = f2bf(b2.y * mq);
          w[6] = f2bf(b2.z * mq); w[7] = f2bf(b2.w * mq);
          *(short8*)&sQn[cbuf][r2b][cb32 + m * 8] = w;
        }
      }
    }
    if (doA && isA) {
      yacc[0] = 0; yacc[1] = 0; oacc[0] = 0; oacc[1] = 0;
      #pragma unroll
      for (int ks = 0; ks < 4; ++ks) {
        short8 ak = *(const short8*)&sKn[pbuf][iy0 + n16][ks * 32 + quad * 8];
        short8 aq = *(const short8*)&sQn[pbuf][iy0 + n16][ks * 32 + quad * 8];
        #pragma unroll
        for (int vt = 0; vt < 2; ++vt) {
          short8 bs = *(const short8*)&sSb[vt * 16 + n16][ks * 32 + quad * 8];
          yacc[vt] = MFMA16(ak, bs, yacc[vt]);
          oacc[vt] = MFMA16(aq, bs, oacc[vt]);
        }
      }
      #pragma unroll
      for (int vt = 0; vt < 2; ++vt) {
        short4v yw;
        #pragma unroll
        for (int reg = 0; reg < 4; ++reg) {
          const float ge = sGe[pbuf][iy0 + quad * 4 + reg];
          yw[reg] = f2bf(ge * (vv[vt][reg] - yacc[vt][reg]));
          oacc[vt][reg] *= ge;
        }
        *(short4v*)&sYT[(vt * 16 + n16) * TST + iy0 + quad * 4] = yw;
      }
    }
    __syncthreads();  // bar1

    // ============ int1: B: PA (KK+QK, balanced) | A: PC -> sCG ============
    if (doB && !isA) {
      f32x4 kacc[4], qacc[4];
      #pragma unroll
      for (int j = 0; j < 4; ++j) { kacc[j] = 0; qacc[j] = 0; }
      const int ik = wb * 16;          // KK i-tile (jt <= wb)
      const int iq = (3 - wb) * 16;    // QK i-tile (jt <= 3-wb): 20 MFMA/wave
      #pragma unroll
      for (int ks = 0; ks < 4; ++ks) {
        short8 akk = *(const short8*)&sKn[cbuf][ik + n16][ks * 32 + quad * 8];
        short8 aqq = *(const short8*)&sQn[cbuf][iq + n16][ks * 32 + quad * 8];
        #pragma unroll
        for (int jt = 0; jt < 4; ++jt) {
          short8 bf = *(const short8*)&sKn[cbuf][jt * 16 + n16][ks * 32 + quad * 8];
          if (jt <= wb)     kacc[jt] = MFMA16(akk, bf, kacc[jt]);
          if (jt <= 3 - wb) qacc[jt] = MFMA16(aqq, bf, qacc[jt]);
        }
      }
      {  // KK epilogue -> strictly-lower A (fp32)
        float sc[4];
        #pragma unroll
        for (int reg = 0; reg < 4; ++reg) {
          const int i = ik + quad * 4 + reg;
          sc[reg] = sBeta[i] * sGi[i];
        }
        #pragma unroll
        for (int jt = 0; jt < 4; ++jt) {
          if (jt <= wb) {
            const int j = jt * 16 + n16;
            const float gej = sGe[cbuf][j];
            #pragma unroll
            for (int reg = 0; reg < 4; ++reg) {
              const int i = ik + quad * 4 + reg;
              if (j < i) sA[i][j] = sc[reg] * gej * kacc[jt][reg];
            }
          }
        }
      }
      {  // QK epilogue -> sAqk[cbuf] (causal, ginv_i-scaled)
        float gi4[4];
        #pragma unroll
        for (int reg = 0; reg < 4; ++reg) gi4[reg] = sGi[iq + quad * 4 + reg];
        #pragma unroll
        for (int jt = 0; jt < 4; ++jt) {
          if (jt <= 3 - wb) {
            #pragma unroll
            for (int reg = 0; reg < 4; ++reg) {
              const int i = iq + quad * 4 + reg, j = jt * 16 + n16;
              sAqk[cbuf][i][j] = (j <= i) ? f2bf(qacc[jt][reg] * gi4[reg]) : (short)0;
            }
          }
        }
      }
    }
    if (doA && isA) {
      #pragma unroll
      for (int vt = 0; vt < 2; ++vt) {
        f32x4 cacc = 0;
        #pragma unroll
        for (int ks = 0; ks < 2; ++ks) {
          short8 af = *(const short8*)&sTb[pbuf][iy0 + n16][ks * 32 + quad * 8];
          short8 bf = *(const short8*)&sYT[(vt * 16 + n16) * TST + ks * 32 + quad * 8];
          cacc = MFMA16(af, bf, cacc);
        }
        short4v cw;
        #pragma unroll
        for (int reg = 0; reg < 4; ++reg)
          cw[reg] = f2bf(cacc[reg] * sGe[pbuf][iy0 + quad * 4 + reg]);
        *(short4v*)&sCG[vt * 16 + n16][iy0 + quad * 4] = cw;
      }
    }
    __syncthreads();  // bar2

    // ==== int2: all prefetch issue; B wave4: S1 (longest) | A: PO + store ====
    if (isA && it < kNC) {  // v for chunk `it` (consumed next iteration)
      #pragma unroll
      for (int vt = 0; vt < 2; ++vt)
        #pragma unroll
        for (int reg = 0; reg < 4; ++reg)
          vv[vt][reg] = vp_g[(size_t)(it * kL + iy0 + quad * 4 + reg) * kDv +
                             vt * 16 + n16];
    }
    if (!isA && it + 1 < kNC) {  // q/k (+gates) for chunk `it+1`
      const float* krow = kp_g + (size_t)((it + 1) * kL + r2b) * kDk + cb32;
      const float* qrow = qp_g + (size_t)((it + 1) * kL + r2b) * kDk + cb32;
      #pragma unroll
      for (int m = 0; m < 8; ++m) {
        kv4[m] = reinterpret_cast<const float4*>(krow)[m];
        qv4[m] = reinterpret_cast<const float4*>(qrow)[m];
      }
      if (wb == 0) {
        gv0 = gp_g[(it + 1) * kL + lane];
        bt0 = bp_g[(it + 1) * kL + lane];
      }
    }
    if (doB && wave == 4) {
      // S1: invert the four 16x16 unit-lower diagonal blocks (64 lanes)
      const int I = lane >> 4, c = lane & 15;
      float x[16];
      #pragma unroll
      for (int i = 0; i < 16; ++i) {
        float xi = (i == c) ? 1.f : 0.f;
        for (int j = 0; j < i; ++j) xi -= sA[I * 16 + i][I * 16 + j] * x[j];
        x[i] = xi;
      }
      const float bc = sBeta[I * 16 + c];
      #pragma unroll
      for (int i = 0; i < 16; ++i) {
        SVINV(I, i, c) = x[i];
        sTb[cbuf][I * 16 + i][I * 16 + c] = f2bf(x[i] * bc);
      }
    }
    if (doA && isA) {
      #pragma unroll
      for (int ks = 0; ks < 2; ++ks) {
        short8 af = *(const short8*)&sAqk[pbuf][iy0 + n16][ks * 32 + quad * 8];
        #pragma unroll
        for (int vt = 0; vt < 2; ++vt) {
          short8 bf = *(const short8*)&sCG[vt * 16 + n16][ks * 32 + quad * 8];
          oacc[vt] = MFMA16(af, bf, oacc[vt]);
        }
      }
      #pragma unroll
      for (int vt = 0; vt < 2; ++vt)
        #pragma unroll
        for (int reg = 0; reg < 4; ++reg)
          op_g[(size_t)((it - 1) * kL + iy0 + quad * 4 + reg) * kDv +
               vt * 16 + n16] = oacc[vt][reg];
    }
    __syncthreads();  // bar3

    // ============ int3: B: S2a | A: PSU gather + decay ============
    short8 afr[2][2];
    if (doB && !isA) {
      const int r = t2 >> 4, c = t2 & 15;
      float m1 = 0.f, m3 = 0.f;
      #pragma unroll
      for (int kk = 0; kk < 16; ++kk) {
        m1 += SVINV(1, r, kk) * sA[16 + kk][c];
        m3 += SVINV(3, r, kk) * sA[48 + kk][32 + c];
      }
      STMP(r, c) = m1;
      STMP(16 + r, c) = m3;
    }
    if (doA && isA) {
      const float decay = sGe[pbuf][kL - 1];
      Sacc[0] *= decay; Sacc[1] *= decay; Sacc[2] *= decay; Sacc[3] *= decay;
      const int d0b = wa * 32;
      #pragma unroll
      for (int a = 0; a < 2; ++a)
        #pragma unroll
        for (int ks = 0; ks < 2; ++ks) {
          short8 af;
          #pragma unroll
          for (int j = 0; j < 8; ++j)
            af[j] = sKn[pbuf][ks * 32 + quad * 8 + j][d0b + a * 16 + n16];
          afr[a][ks] = af;
        }
    }
    __syncthreads();  // bar4

    // ============ int4: B: S2b | A: PSU MFMA + S^T snapshot ============
    if (doB && !isA) {
      const int r = t2 >> 4, c = t2 & 15;
      float x1 = 0.f, x3 = 0.f;
      #pragma unroll
      for (int kk = 0; kk < 16; ++kk) {
        x1 += STMP(r, kk) * SVINV(0, kk, c);
        x3 += STMP(16 + r, kk) * SVINV(2, kk, c);
      }
      x1 = -x1; x3 = -x3;
      sA[16 + r][c] = x1;
      sTb[cbuf][16 + r][c] = f2bf(x1 * sBeta[c]);
      sA[48 + r][32 + c] = x3;
      sTb[cbuf][48 + r][32 + c] = f2bf(x3 * sBeta[32 + c]);
    }
    if (doA && isA) {
      const int d0b = wa * 32;
      #pragma unroll
      for (int a = 0; a < 2; ++a) {
        #pragma unroll
        for (int ks = 0; ks < 2; ++ks) {
          #pragma unroll
          for (int b = 0; b < 2; ++b) {
            short8 bf = *(const short8*)&sCG[b * 16 + n16][ks * 32 + quad * 8];
            Sacc[a * 2 + b] = MFMA16(afr[a][ks], bf, Sacc[a * 2 + b]);
          }
        }
        #pragma unroll
        for (int b = 0; b < 2; ++b) {
          short4v sw;
          #pragma unroll
          for (int reg = 0; reg < 4; ++reg) sw[reg] = f2bf(Sacc[a * 2 + b][reg]);
          *(short4v*)&sSb[b * 16 + n16][d0b + a * 16 + quad * 4] = sw;
        }
      }
    }
    __syncthreads();  // bar5

    // ============ int5: B: S3a ============
    if (doB && !isA) {
      #pragma unroll
      for (int p = 0; p < 4; ++p) {
        const int idx = t2 + 256 * p;
        const int r = idx >> 5, c = idx & 31;
        float m = 0.f;
        if (c < 16) {
          #pragma unroll
          for (int kk = 0; kk < 16; ++kk) m += sA[32 + r][kk] * SVINV(0, kk, c);
          #pragma unroll
          for (int kk = 16; kk < 32; ++kk) m += sA[32 + r][kk] * sA[kk][c];
        } else {
          #pragma unroll
          for (int kk = 16; kk < 32; ++kk)
            m += sA[32 + r][kk] * SVINV(1, kk - 16, c - 16);
        }
        STMP(r, c) = m;
      }
    }
    __syncthreads();  // bar6

    // ============ int6: B: S3b -> sTb lower-left ============
    if (doB && !isA) {
      #pragma unroll
      for (int p = 0; p < 4; ++p) {
        const int idx = t2 + 256 * p;
        const int r = idx >> 5, c = idx & 31;
        float xv = 0.f;
        if (r < 16) {
          #pragma unroll
          for (int kk = 0; kk < 16; ++kk) xv += SVINV(2, r, kk) * STMP(kk, c);
        } else {
          #pragma unroll
          for (int kk = 0; kk < 16; ++kk) xv += sA[32 + r][32 + kk] * STMP(kk, c);
          #pragma unroll
          for (int kk = 16; kk < 32; ++kk)
            xv += SVINV(3, r - 16, kk - 16) * STMP(kk, c);
        }
        sTb[cbuf][32 + r][c] = f2bf(-xv * sBeta[c]);
      }
    }
    __syncthreads();  // bar7
  }

  // ---- final state (fp32 from accumulators) -> d_out tail ----
  if (isA) {
    const int d0b = wa * 32;
    #pragma unroll
    for (int a = 0; a < 2; ++a)
      #pragma unroll
      for (int b = 0; b < 2; ++b)
        #pragma unroll
        for (int reg = 0; reg < 4; ++reg) {
          const int d = d0b + a * 16 + quad * 4 + reg;
          sp_g[(size_t)d * kDv + b * 16 + n16] = Sacc[a * 2 + b][reg];
        }
  }
#undef SVINV
#undef STMP
}

}  // namespace

extern "C" void kernel_launch(void* const* d_in, const int* in_sizes, int n_in,
                              void* d_out, int out_size, void* d_ws, size_t ws_size,
                              hipStream_t stream) {
  (void)in_sizes; (void)n_in; (void)d_ws; (void)ws_size; (void)out_size;
  const float* q    = (const float*)d_in[0];
  const float* k    = (const float*)d_in[1];
  const float* v    = (const float*)d_in[2];
  const float* g    = (const float*)d_in[3];
  const float* beta = (const float*)d_in[4];
  float* out = (float*)d_out;
  gdn_mfma_kernel<<<dim3(kBH * (kDv / 32)), dim3(kThreads), 0, stream>>>(
      q, k, v, g, beta, out);
}

// Round 3
// 933.373 us; speedup vs baseline: 1.8847x; 1.3931x over previous
//
#include <hip/hip_runtime.h>
#include <math.h>

// Gated DeltaNet chunkwise recurrence on MFMA (gfx950).
// V4 = V1's proven 8-wave schedule + three latency cuts:
//  (a) V3's verified ungated-operand algebra: only kn=k/||k||, qn=scale*q/||q||
//      staged in bf16; decay gates applied in fp32 epilogues.
//  (b) cross-chunk register prefetch of q/k/g/beta (issued at stage2, consumed
//      next chunk) - removes chunk-head global-load latency.
//  (c) norms + gate cumsum hoisted into the previous chunk's PC interval
//      (gates double-buffered in LDS, norms in regs) - merges V1's b0/b1.
// grid = 32 heads x 8 v-slices (32 cols); 512 thr; 9 barriers/chunk.
// Algebra:
//   A[i][j]    = beta_i * ginv_i * gexp_j * (kn_i.kn_j)   (j<i)
//   Aqk2[i][j] = ginv_i * (qn_i.kn_j)                     (j<=i)
//   Y[i]  = gexp_i * (V[i] - kn_i.S)
//   corg  = gexp_i * (T.Y)
//   O[i]  = gexp_i * (qn_i.S) + Aqk2.corg
//   S'    = decay * S + kn^T.corg

namespace {

constexpr int kBH = 32;
constexpr int kS = 4096;
constexpr int kDk = 128;
constexpr int kDv = 256;
constexpr int kL = 64;
constexpr int kNC = kS / kL;
constexpr int kThreads = 512;
constexpr float kScale = 0.08838834764831845f;  // 128^-0.5
constexpr float kEps = 1e-6f;

constexpr int KST = 136;  // bf16 row stride, 128-col mats
constexpr int TST = 72;   // bf16 row stride, 64-col mats
constexpr int SBT = 136;  // bf16 row stride for S^T snapshot
constexpr int AS  = 68;   // fp32 row stride for A / solve

typedef __attribute__((ext_vector_type(8))) short short8;
typedef __attribute__((ext_vector_type(4))) short short4v;
typedef __attribute__((ext_vector_type(4))) float f32x4;

__device__ __forceinline__ short f2bf(float f) {
  union { float f; unsigned u; } x;
  x.f = f;
  unsigned r = x.u + 0x7fffu + ((x.u >> 16) & 1u);  // RNE
  return (short)(r >> 16);
}

#define MFMA16(a, b, c) __builtin_amdgcn_mfma_f32_16x16x32_bf16((a), (b), (c), 0, 0, 0)

__global__ __launch_bounds__(kThreads, 2)
void gdn_mfma_kernel(const float* __restrict__ q, const float* __restrict__ k,
                     const float* __restrict__ v, const float* __restrict__ g,
                     const float* __restrict__ beta, float* __restrict__ out) {
  __shared__ __align__(16) short sKn[kL][KST];   // k/||k||            17408 B
  __shared__ __align__(16) short sQn[kL][KST];   // scale*q/||q||      17408 B
  __shared__ __align__(16) short sTb[kL][TST];   // T bf16 (upper 0)    9216 B
  __shared__ __align__(16) short sAqk[kL][TST];  // ginv-scaled qk      9216 B
  __shared__ __align__(16) short sSb[32][SBT];   // S^T snapshot bf16   8704 B
  __shared__ __align__(16) float sA[kL][AS];     // strictly-lower A   17408 B
  __shared__ __align__(16) float sVinv[4][16][17];                   // 4352 B
  __shared__ __align__(16) float sTmp[32][33];                       // 4224 B
  __shared__ __align__(16) short sYT[32][TST];   // Y^T bf16            4608 B
  __shared__ __align__(16) short sCT[32][TST];   // corg^T bf16         4608 B
  __shared__ __align__(16) float sGe[2][kL];     // exp(+gcum), dbuf     512 B
  __shared__ __align__(16) float sGi[2][kL];     // exp(-gcum), dbuf     512 B
  __shared__ __align__(16) float sBeta[2][kL];   //                      512 B
  // total 98688 B -> 1 WG/CU

  const int t = threadIdx.x;
  const int wave = t >> 6;
  const int lane = t & 63;
  const int n16 = lane & 15;
  const int quad = lane >> 4;
  const int r2 = t >> 3;  // 0..63 staging row
  const int c8 = t & 7;   // 16-col group within row
  const int iy0 = (wave & 3) * 16;

  const int bh = blockIdx.x & 31;
  const int vb = blockIdx.x >> 5;

  const float* qp_g = q + (size_t)bh * kS * kDk;
  const float* kp_g = k + (size_t)bh * kS * kDk;
  const float* vp_g = v + (size_t)bh * kS * kDv + vb * 32;
  const float* gp_g = g + (size_t)bh * kS;
  const float* bp_g = beta + (size_t)bh * kS;
  float* op_g = out + (size_t)bh * kS * kDv + vb * 32;
  float* sp_g = out + (size_t)kBH * kS * kDv + (size_t)bh * kDk * kDv + vb * 32;

  // persistent-zero regions (upper triangles never rewritten) + S^T snapshot
  for (int i = t; i < kL * TST; i += kThreads) { (&sTb[0][0])[i] = 0; (&sAqk[0][0])[i] = 0; }
  for (int i = t; i < 32 * SBT; i += kThreads) (&sSb[0][0])[i] = 0;

  f32x4 Sacc[4];  // waves 0-3: state tiles (d0 = wa*32 + a*16, v0 = b*16)
  Sacc[0] = 0; Sacc[1] = 0; Sacc[2] = 0; Sacc[3] = 0;

  float4 kv4[4], qv4[4];    // prefetched q/k rows (16 floats each)
  float gv0 = 0.f, bt0 = 0.f;
  float krk = 0.f, krq = 0.f;

  // ---- prologue: chunk-0 loads + norms + gates (buffer 0) ----
  {
    const float* krow = kp_g + (size_t)r2 * kDk + c8 * 16;
    const float* qrow = qp_g + (size_t)r2 * kDk + c8 * 16;
    #pragma unroll
    for (int m = 0; m < 4; ++m) {
      kv4[m] = reinterpret_cast<const float4*>(krow)[m];
      qv4[m] = reinterpret_cast<const float4*>(qrow)[m];
    }
    if (t < kL) { gv0 = gp_g[t]; bt0 = bp_g[t]; }
    float ssk = 0.f, ssq = 0.f;
    #pragma unroll
    for (int m = 0; m < 4; ++m) {
      ssk += kv4[m].x * kv4[m].x + kv4[m].y * kv4[m].y +
             kv4[m].z * kv4[m].z + kv4[m].w * kv4[m].w;
      ssq += qv4[m].x * qv4[m].x + qv4[m].y * qv4[m].y +
             qv4[m].z * qv4[m].z + qv4[m].w * qv4[m].w;
    }
    #pragma unroll
    for (int off = 4; off >= 1; off >>= 1) {
      ssk += __shfl_xor(ssk, off, 8);
      ssq += __shfl_xor(ssq, off, 8);
    }
    krk = 1.f / (sqrtf(ssk) + kEps);
    krq = kScale / (sqrtf(ssq) + kEps);
    if (t < kL) {
      float gv = gv0;
      #pragma unroll
      for (int off = 1; off < 64; off <<= 1) {
        float up = __shfl_up(gv, off, 64);
        if (lane >= off) gv += up;
      }
      sGe[0][t] = __expf(gv);
      sGi[0][t] = __expf(-gv);
      sBeta[0][t] = bt0;
    }
  }

  for (int n = 0; n < kNC; ++n) {
    const int cb = n & 1;
    __syncthreads();  // b0: previous chunk fully consumed; gates/operands ready

    // ---- stage2: write the two ungated bf16 operand matrices ----
    {
      const float mk = krk, mq = krq;
      #pragma unroll
      for (int m = 0; m < 2; ++m) {
        const float4 a = kv4[2 * m], b2 = kv4[2 * m + 1];
        short8 w;
        w[0] = f2bf(a.x * mk);  w[1] = f2bf(a.y * mk);
        w[2] = f2bf(a.z * mk);  w[3] = f2bf(a.w * mk);
        w[4] = f2bf(b2.x * mk); w[5] = f2bf(b2.y * mk);
        w[6] = f2bf(b2.z * mk); w[7] = f2bf(b2.w * mk);
        *(short8*)&sKn[r2][c8 * 16 + m * 8] = w;
      }
      #pragma unroll
      for (int m = 0; m < 2; ++m) {
        const float4 a = qv4[2 * m], b2 = qv4[2 * m + 1];
        short8 w;
        w[0] = f2bf(a.x * mq);  w[1] = f2bf(a.y * mq);
        w[2] = f2bf(a.z * mq);  w[3] = f2bf(a.w * mq);
        w[4] = f2bf(b2.x * mq); w[5] = f2bf(b2.y * mq);
        w[6] = f2bf(b2.z * mq); w[7] = f2bf(b2.w * mq);
        *(short8*)&sQn[r2][c8 * 16 + m * 8] = w;
      }
    }
    // ---- prefetch chunk n+1 q/k/g/beta into regs (consumed next chunk) ----
    if (n + 1 < kNC) {
      const float* krow = kp_g + (size_t)((n + 1) * kL + r2) * kDk + c8 * 16;
      const float* qrow = qp_g + (size_t)((n + 1) * kL + r2) * kDk + c8 * 16;
      #pragma unroll
      for (int m = 0; m < 4; ++m) {
        kv4[m] = reinterpret_cast<const float4*>(krow)[m];
        qv4[m] = reinterpret_cast<const float4*>(qrow)[m];
      }
      if (t < kL) {
        gv0 = gp_g[(n + 1) * kL + t];
        bt0 = bp_g[(n + 1) * kL + t];
      }
    }
    __syncthreads();  // b2: operands visible

    // ---- PA: KK (waves 0-3 -> strictly-lower A) / QK (waves 4-7 -> Aqk) ----
    float vv[2][4];
    {
      const int jmax = wave & 3;
      const short (*Asrc)[KST] = (wave < 4) ? sKn : sQn;
      f32x4 acc[4];
      acc[0] = 0; acc[1] = 0; acc[2] = 0; acc[3] = 0;
      if (wave >= 4) {  // issue v loads early; consumed at the Y epilogue
        #pragma unroll
        for (int vt = 0; vt < 2; ++vt)
          #pragma unroll
          for (int reg = 0; reg < 4; ++reg)
            vv[vt][reg] = vp_g[(size_t)(n * kL + iy0 + quad * 4 + reg) * kDv +
                               vt * 16 + n16];
      }
      #pragma unroll
      for (int ks = 0; ks < 4; ++ks) {
        short8 af = *(const short8*)&Asrc[iy0 + n16][ks * 32 + quad * 8];
        for (int jt = 0; jt <= jmax; ++jt) {
          short8 bf = *(const short8*)&sKn[jt * 16 + n16][ks * 32 + quad * 8];
          acc[jt] = MFMA16(af, bf, acc[jt]);
        }
      }
      if (wave < 4) {
        float sc[4];
        #pragma unroll
        for (int reg = 0; reg < 4; ++reg) {
          const int i = iy0 + quad * 4 + reg;
          sc[reg] = sBeta[cb][i] * sGi[cb][i];
        }
        for (int jt = 0; jt <= jmax; ++jt) {
          const int j = jt * 16 + n16;
          const float gej = sGe[cb][j];
          #pragma unroll
          for (int reg = 0; reg < 4; ++reg) {
            const int i = iy0 + quad * 4 + reg;
            if (j < i) sA[i][j] = sc[reg] * gej * acc[jt][reg];
          }
        }
      } else {
        float gi4[4];
        #pragma unroll
        for (int reg = 0; reg < 4; ++reg) gi4[reg] = sGi[cb][iy0 + quad * 4 + reg];
        for (int jt = 0; jt <= jmax; ++jt) {
          #pragma unroll
          for (int reg = 0; reg < 4; ++reg) {
            const int i = iy0 + quad * 4 + reg, j = jt * 16 + n16;
            sAqk[i][j] = (j <= i) ? f2bf(acc[jt][reg] * gi4[reg]) : (short)0;
          }
        }
      }
    }
    __syncthreads();  // b3

    // ---- interleaved: solve (waves 0-3, fp32) || PY = [kn;qn].S (waves 4-7) ----
    f32x4 yacc[2], oacc[2];
    auto py_step = [&](int ks) {
      short8 ak = *(const short8*)&sKn[iy0 + n16][ks * 32 + quad * 8];
      short8 aq = *(const short8*)&sQn[iy0 + n16][ks * 32 + quad * 8];
      #pragma unroll
      for (int vt = 0; vt < 2; ++vt) {
        short8 bs = *(const short8*)&sSb[vt * 16 + n16][ks * 32 + quad * 8];
        yacc[vt] = MFMA16(ak, bs, yacc[vt]);
        oacc[vt] = MFMA16(aq, bs, oacc[vt]);
      }
    };

    if (wave >= 4) {
      yacc[0] = 0; yacc[1] = 0; oacc[0] = 0; oacc[1] = 0;
      py_step(0);
    } else if (t < 64) {
      // S1: invert the four 16x16 unit-lower diagonal blocks
      const int I = t >> 4, c = t & 15;
      float x[16];
      #pragma unroll
      for (int i = 0; i < 16; ++i) {
        float xi = (i == c) ? 1.f : 0.f;
        for (int j = 0; j < i; ++j) xi -= sA[I * 16 + i][I * 16 + j] * x[j];
        x[i] = xi;
      }
      const float bc = sBeta[cb][I * 16 + c];
      #pragma unroll
      for (int i = 0; i < 16; ++i) {
        sVinv[I][i][c] = x[i];
        sTb[I * 16 + i][I * 16 + c] = f2bf(x[i] * bc);
      }
    }
    __syncthreads();  // b4

    if (wave >= 4) {
      py_step(1);
    } else {
      // S2a: M10 = V1*A10, M32 = V3*A32   (t < 256)
      const int r = t >> 4, c = t & 15;
      float m1 = 0.f, m3 = 0.f;
      #pragma unroll
      for (int kk = 0; kk < 16; ++kk) {
        m1 += sVinv[1][r][kk] * sA[16 + kk][c];
        m3 += sVinv[3][r][kk] * sA[48 + kk][32 + c];
      }
      sTmp[r][c] = m1;
      sTmp[16 + r][c] = m3;
    }
    __syncthreads();  // b5

    if (wave >= 4) {
      py_step(2);
    } else {
      // S2b: X10 = -M10*V0 ; X32 = -M32*V2
      const int r = t >> 4, c = t & 15;
      float x1 = 0.f, x3 = 0.f;
      #pragma unroll
      for (int kk = 0; kk < 16; ++kk) {
        x1 += sTmp[r][kk] * sVinv[0][kk][c];
        x3 += sTmp[16 + r][kk] * sVinv[2][kk][c];
      }
      x1 = -x1; x3 = -x3;
      sA[16 + r][c] = x1;
      sTb[16 + r][c] = f2bf(x1 * sBeta[cb][c]);
      sA[48 + r][32 + c] = x3;
      sTb[48 + r][32 + c] = f2bf(x3 * sBeta[cb][32 + c]);
    }
    __syncthreads();  // b6

    if (wave >= 4) {
      py_step(3);
    } else {
      // S3a: M = A_bl * W1inv  (32x32), W1inv = [[V0,0],[X10,V1]]
      #pragma unroll
      for (int p = 0; p < 4; ++p) {
        const int idx = t + 256 * p;
        const int r = idx >> 5, c = idx & 31;
        float m = 0.f;
        if (c < 16) {
          #pragma unroll
          for (int kk = 0; kk < 16; ++kk) m += sA[32 + r][kk] * sVinv[0][kk][c];
          #pragma unroll
          for (int kk = 16; kk < 32; ++kk) m += sA[32 + r][kk] * sA[kk][c];
        } else {
          #pragma unroll
          for (int kk = 16; kk < 32; ++kk)
            m += sA[32 + r][kk] * sVinv[1][kk - 16][c - 16];
        }
        sTmp[r][c] = m;
      }
    }
    __syncthreads();  // b7

    // ---- b7-b8: waves 4-7: Y epilogue -> sYT ; waves 0-3: S3b ----
    if (wave >= 4) {
      #pragma unroll
      for (int vt = 0; vt < 2; ++vt) {
        short4v yw;
        #pragma unroll
        for (int reg = 0; reg < 4; ++reg) {
          const float ge = sGe[cb][iy0 + quad * 4 + reg];
          yw[reg] = f2bf(ge * (vv[vt][reg] - yacc[vt][reg]));
          oacc[vt][reg] *= ge;
        }
        *(short4v*)&sYT[vt * 16 + n16][iy0 + quad * 4] = yw;
      }
    } else {
      // S3b: X_bl = -W2inv * M, W2inv = [[V2,0],[X32,V3]]
      #pragma unroll
      for (int p = 0; p < 4; ++p) {
        const int idx = t + 256 * p;
        const int r = idx >> 5, c = idx & 31;
        float xv = 0.f;
        if (r < 16) {
          #pragma unroll
          for (int kk = 0; kk < 16; ++kk) xv += sVinv[2][r][kk] * sTmp[kk][c];
        } else {
          #pragma unroll
          for (int kk = 0; kk < 16; ++kk) xv += sA[32 + r][32 + kk] * sTmp[kk][c];
          #pragma unroll
          for (int kk = 16; kk < 32; ++kk)
            xv += sVinv[3][r - 16][kk - 16] * sTmp[kk][c];
        }
        sTb[32 + r][c] = f2bf(-xv * sBeta[cb][c]);
      }
    }
    __syncthreads();  // b8

    // ---- PC: corg^T = gexp_i*(T.Y)^T (all 8 waves) ; + next-chunk norms/gates ----
    {
      const int ic0 = (wave >> 1) * 16, vc0 = (wave & 1) * 16;
      f32x4 cacc; cacc = 0;
      #pragma unroll
      for (int ks = 0; ks < 2; ++ks) {
        short8 af = *(const short8*)&sTb[ic0 + n16][ks * 32 + quad * 8];
        short8 bf = *(const short8*)&sYT[vc0 + n16][ks * 32 + quad * 8];
        cacc = MFMA16(af, bf, cacc);
      }
      short4v cw;
      #pragma unroll
      for (int reg = 0; reg < 4; ++reg)
        cw[reg] = f2bf(cacc[reg] * sGe[cb][ic0 + quad * 4 + reg]);
      *(short4v*)&sCT[vc0 + n16][ic0 + quad * 4] = cw;
    }
    if (n + 1 < kNC) {
      // norms for chunk n+1 (prefetched regs; loads landed barriers ago)
      float ssk = 0.f, ssq = 0.f;
      #pragma unroll
      for (int m = 0; m < 4; ++m) {
        ssk += kv4[m].x * kv4[m].x + kv4[m].y * kv4[m].y +
               kv4[m].z * kv4[m].z + kv4[m].w * kv4[m].w;
        ssq += qv4[m].x * qv4[m].x + qv4[m].y * qv4[m].y +
               qv4[m].z * qv4[m].z + qv4[m].w * qv4[m].w;
      }
      #pragma unroll
      for (int off = 4; off >= 1; off >>= 1) {
        ssk += __shfl_xor(ssk, off, 8);
        ssq += __shfl_xor(ssq, off, 8);
      }
      krk = 1.f / (sqrtf(ssk) + kEps);
      krq = kScale / (sqrtf(ssq) + kEps);
      if (t < kL) {  // gate cumsum for chunk n+1 -> buffer cb^1
        float gv = gv0;
        #pragma unroll
        for (int off = 1; off < 64; off <<= 1) {
          float up = __shfl_up(gv, off, 64);
          if (lane >= off) gv += up;
        }
        sGe[cb ^ 1][t] = __expf(gv);
        sGi[cb ^ 1][t] = __expf(-gv);
        sBeta[cb ^ 1][t] = bt0;
      }
    }
    __syncthreads();  // b9

    // ---- PO (waves 4-7): O = gexp*qn.S + Aqk2.corg -> global
    // ---- PSU (waves 0-3): S = decay*S + kn^T.corg (in accumulators) ----
    if (wave >= 4) {
      const int io = (wave & 3) * 16;
      #pragma unroll
      for (int ks = 0; ks < 2; ++ks) {
        short8 af = *(const short8*)&sAqk[io + n16][ks * 32 + quad * 8];
        #pragma unroll
        for (int vt = 0; vt < 2; ++vt) {
          short8 bf = *(const short8*)&sCT[vt * 16 + n16][ks * 32 + quad * 8];
          oacc[vt] = MFMA16(af, bf, oacc[vt]);
        }
      }
      #pragma unroll
      for (int vt = 0; vt < 2; ++vt)
        #pragma unroll
        for (int reg = 0; reg < 4; ++reg)
          op_g[(size_t)(n * kL + io + quad * 4 + reg) * kDv + vt * 16 + n16] =
              oacc[vt][reg];
    } else {
      const float decay = sGe[cb][kL - 1];
      Sacc[0] *= decay; Sacc[1] *= decay; Sacc[2] *= decay; Sacc[3] *= decay;
      #pragma unroll
      for (int a = 0; a < 2; ++a) {
        const int d0 = (wave & 3) * 32 + a * 16;
        #pragma unroll
        for (int ks = 0; ks < 2; ++ks) {
          short8 af;
          #pragma unroll
          for (int j = 0; j < 8; ++j) af[j] = sKn[ks * 32 + quad * 8 + j][d0 + n16];
          #pragma unroll
          for (int b = 0; b < 2; ++b) {
            short8 bf = *(const short8*)&sCT[b * 16 + n16][ks * 32 + quad * 8];
            Sacc[a * 2 + b] = MFMA16(af, bf, Sacc[a * 2 + b]);
          }
        }
        #pragma unroll
        for (int b = 0; b < 2; ++b) {
          short4v sw;
          #pragma unroll
          for (int reg = 0; reg < 4; ++reg) sw[reg] = f2bf(Sacc[a * 2 + b][reg]);
          *(short4v*)&sSb[b * 16 + n16][d0 + quad * 4] = sw;
        }
      }
    }
  }

  // ---- final state (fp32 from accumulators) -> d_out tail ----
  if (wave < 4) {
    #pragma unroll
    for (int a = 0; a < 2; ++a)
      #pragma unroll
      for (int b = 0; b < 2; ++b)
        #pragma unroll
        for (int reg = 0; reg < 4; ++reg) {
          const int d = (wave & 3) * 32 + a * 16 + quad * 4 + reg;
          sp_g[(size_t)d * kDv + b * 16 + n16] = Sacc[a * 2 + b][reg];
        }
  }
}

}  // namespace

extern "C" void kernel_launch(void* const* d_in, const int* in_sizes, int n_in,
                              void* d_out, int out_size, void* d_ws, size_t ws_size,
                              hipStream_t stream) {
  (void)in_sizes; (void)n_in; (void)d_ws; (void)ws_size; (void)out_size;
  const float* q    = (const float*)d_in[0];
  const float* k    = (const float*)d_in[1];
  const float* v    = (const float*)d_in[2];
  const float* g    = (const float*)d_in[3];
  const float* beta = (const float*)d_in[4];
  float* out = (float*)d_out;
  gdn_mfma_kernel<<<dim3(kBH * (kDv / 32)), dim3(kThreads), 0, stream>>>(
      q, k, v, g, beta, out);
}

// Round 4
// 916.629 us; speedup vs baseline: 1.9191x; 1.0183x over previous
//
#include <hip/hip_runtime.h>
#include <math.h>

// Gated DeltaNet chunkwise recurrence on MFMA (gfx950).
// V5 = V4 + raw-barrier scheduling: every __syncthreads() is replaced by
//   s_waitcnt lgkmcnt(0) ; s_barrier        (inline asm, "memory" clobber)
// which preserves all LDS producer->consumer ordering but does NOT drain
// vmcnt. hipcc's __syncthreads emits `s_waitcnt vmcnt(0)` before s_barrier,
// which was force-completing the cross-chunk q/k register prefetch at b2,
// the v loads at b3, and the O store ack at the next b0 - putting every
// global round-trip on the critical path. Raw barriers let those stay in
// flight; the compiler still inserts vmcnt waits at register-use sites.
// Everything else is V4 (verified): ungated kn/qn operands, fp32 epilogue
// gating, cross-chunk prefetch, hoisted norms/gate-scan, 8-wave schedule.
// Algebra:
//   A[i][j]    = beta_i * ginv_i * gexp_j * (kn_i.kn_j)   (j<i)
//   Aqk2[i][j] = ginv_i * (qn_i.kn_j)                     (j<=i)
//   Y[i]  = gexp_i * (V[i] - kn_i.S)
//   corg  = gexp_i * (T.Y)
//   O[i]  = gexp_i * (qn_i.S) + Aqk2.corg
//   S'    = decay * S + kn^T.corg

namespace {

constexpr int kBH = 32;
constexpr int kS = 4096;
constexpr int kDk = 128;
constexpr int kDv = 256;
constexpr int kL = 64;
constexpr int kNC = kS / kL;
constexpr int kThreads = 512;
constexpr float kScale = 0.08838834764831845f;  // 128^-0.5
constexpr float kEps = 1e-6f;

constexpr int KST = 136;  // bf16 row stride, 128-col mats
constexpr int TST = 72;   // bf16 row stride, 64-col mats
constexpr int SBT = 136;  // bf16 row stride for S^T snapshot
constexpr int AS  = 68;   // fp32 row stride for A / solve

typedef __attribute__((ext_vector_type(8))) short short8;
typedef __attribute__((ext_vector_type(4))) short short4v;
typedef __attribute__((ext_vector_type(4))) float f32x4;

__device__ __forceinline__ short f2bf(float f) {
  union { float f; unsigned u; } x;
  x.f = f;
  unsigned r = x.u + 0x7fffu + ((x.u >> 16) & 1u);  // RNE
  return (short)(r >> 16);
}

// Workgroup barrier WITHOUT the vmcnt(0) drain __syncthreads would emit.
// lgkmcnt(0) orders all LDS traffic (RAW: producers drained before arrival;
// WAR: readers drained before arrival). Global loads keep their
// compiler-inserted vmcnt waits at the register-use site; global stores
// (O, final state) have no reader and need no wait.
__device__ __forceinline__ void wg_barrier() {
  asm volatile("s_waitcnt lgkmcnt(0)\n\ts_barrier" ::: "memory");
}

#define MFMA16(a, b, c) __builtin_amdgcn_mfma_f32_16x16x32_bf16((a), (b), (c), 0, 0, 0)

__global__ __launch_bounds__(kThreads, 2)
void gdn_mfma_kernel(const float* __restrict__ q, const float* __restrict__ k,
                     const float* __restrict__ v, const float* __restrict__ g,
                     const float* __restrict__ beta, float* __restrict__ out) {
  __shared__ __align__(16) short sKn[kL][KST];   // k/||k||            17408 B
  __shared__ __align__(16) short sQn[kL][KST];   // scale*q/||q||      17408 B
  __shared__ __align__(16) short sTb[kL][TST];   // T bf16 (upper 0)    9216 B
  __shared__ __align__(16) short sAqk[kL][TST];  // ginv-scaled qk      9216 B
  __shared__ __align__(16) short sSb[32][SBT];   // S^T snapshot bf16   8704 B
  __shared__ __align__(16) float sA[kL][AS];     // strictly-lower A   17408 B
  __shared__ __align__(16) float sVinv[4][16][17];                   // 4352 B
  __shared__ __align__(16) float sTmp[32][33];                       // 4224 B
  __shared__ __align__(16) short sYT[32][TST];   // Y^T bf16            4608 B
  __shared__ __align__(16) short sCT[32][TST];   // corg^T bf16         4608 B
  __shared__ __align__(16) float sGe[2][kL];     // exp(+gcum), dbuf     512 B
  __shared__ __align__(16) float sGi[2][kL];     // exp(-gcum), dbuf     512 B
  __shared__ __align__(16) float sBeta[2][kL];   //                      512 B
  // total 98688 B -> 1 WG/CU

  const int t = threadIdx.x;
  const int wave = t >> 6;
  const int lane = t & 63;
  const int n16 = lane & 15;
  const int quad = lane >> 4;
  const int r2 = t >> 3;  // 0..63 staging row
  const int c8 = t & 7;   // 16-col group within row
  const int iy0 = (wave & 3) * 16;

  const int bh = blockIdx.x & 31;
  const int vb = blockIdx.x >> 5;

  const float* qp_g = q + (size_t)bh * kS * kDk;
  const float* kp_g = k + (size_t)bh * kS * kDk;
  const float* vp_g = v + (size_t)bh * kS * kDv + vb * 32;
  const float* gp_g = g + (size_t)bh * kS;
  const float* bp_g = beta + (size_t)bh * kS;
  float* op_g = out + (size_t)bh * kS * kDv + vb * 32;
  float* sp_g = out + (size_t)kBH * kS * kDv + (size_t)bh * kDk * kDv + vb * 32;

  // persistent-zero regions (upper triangles never rewritten) + S^T snapshot
  for (int i = t; i < kL * TST; i += kThreads) { (&sTb[0][0])[i] = 0; (&sAqk[0][0])[i] = 0; }
  for (int i = t; i < 32 * SBT; i += kThreads) (&sSb[0][0])[i] = 0;

  f32x4 Sacc[4];  // waves 0-3: state tiles (d0 = wa*32 + a*16, v0 = b*16)
  Sacc[0] = 0; Sacc[1] = 0; Sacc[2] = 0; Sacc[3] = 0;

  float4 kv4[4], qv4[4];    // prefetched q/k rows (16 floats each)
  float gv0 = 0.f, bt0 = 0.f;
  float krk = 0.f, krq = 0.f;

  // ---- prologue: chunk-0 loads + norms + gates (buffer 0) ----
  {
    const float* krow = kp_g + (size_t)r2 * kDk + c8 * 16;
    const float* qrow = qp_g + (size_t)r2 * kDk + c8 * 16;
    #pragma unroll
    for (int m = 0; m < 4; ++m) {
      kv4[m] = reinterpret_cast<const float4*>(krow)[m];
      qv4[m] = reinterpret_cast<const float4*>(qrow)[m];
    }
    if (t < kL) { gv0 = gp_g[t]; bt0 = bp_g[t]; }
    float ssk = 0.f, ssq = 0.f;
    #pragma unroll
    for (int m = 0; m < 4; ++m) {
      ssk += kv4[m].x * kv4[m].x + kv4[m].y * kv4[m].y +
             kv4[m].z * kv4[m].z + kv4[m].w * kv4[m].w;
      ssq += qv4[m].x * qv4[m].x + qv4[m].y * qv4[m].y +
             qv4[m].z * qv4[m].z + qv4[m].w * qv4[m].w;
    }
    #pragma unroll
    for (int off = 4; off >= 1; off >>= 1) {
      ssk += __shfl_xor(ssk, off, 8);
      ssq += __shfl_xor(ssq, off, 8);
    }
    krk = 1.f / (sqrtf(ssk) + kEps);
    krq = kScale / (sqrtf(ssq) + kEps);
    if (t < kL) {
      float gv = gv0;
      #pragma unroll
      for (int off = 1; off < 64; off <<= 1) {
        float up = __shfl_up(gv, off, 64);
        if (lane >= off) gv += up;
      }
      sGe[0][t] = __expf(gv);
      sGi[0][t] = __expf(-gv);
      sBeta[0][t] = bt0;
    }
  }

  for (int n = 0; n < kNC; ++n) {
    const int cb = n & 1;
    wg_barrier();  // b0: previous chunk fully consumed; gates/operands ready

    // ---- stage2: write the two ungated bf16 operand matrices ----
    {
      const float mk = krk, mq = krq;
      #pragma unroll
      for (int m = 0; m < 2; ++m) {
        const float4 a = kv4[2 * m], b2 = kv4[2 * m + 1];
        short8 w;
        w[0] = f2bf(a.x * mk);  w[1] = f2bf(a.y * mk);
        w[2] = f2bf(a.z * mk);  w[3] = f2bf(a.w * mk);
        w[4] = f2bf(b2.x * mk); w[5] = f2bf(b2.y * mk);
        w[6] = f2bf(b2.z * mk); w[7] = f2bf(b2.w * mk);
        *(short8*)&sKn[r2][c8 * 16 + m * 8] = w;
      }
      #pragma unroll
      for (int m = 0; m < 2; ++m) {
        const float4 a = qv4[2 * m], b2 = qv4[2 * m + 1];
        short8 w;
        w[0] = f2bf(a.x * mq);  w[1] = f2bf(a.y * mq);
        w[2] = f2bf(a.z * mq);  w[3] = f2bf(a.w * mq);
        w[4] = f2bf(b2.x * mq); w[5] = f2bf(b2.y * mq);
        w[6] = f2bf(b2.z * mq); w[7] = f2bf(b2.w * mq);
        *(short8*)&sQn[r2][c8 * 16 + m * 8] = w;
      }
    }
    // ---- prefetch chunk n+1 q/k/g/beta into regs (consumed next chunk;
    //      with raw barriers these loads stay in flight across the solve) ----
    if (n + 1 < kNC) {
      const float* krow = kp_g + (size_t)((n + 1) * kL + r2) * kDk + c8 * 16;
      const float* qrow = qp_g + (size_t)((n + 1) * kL + r2) * kDk + c8 * 16;
      #pragma unroll
      for (int m = 0; m < 4; ++m) {
        kv4[m] = reinterpret_cast<const float4*>(krow)[m];
        qv4[m] = reinterpret_cast<const float4*>(qrow)[m];
      }
      if (t < kL) {
        gv0 = gp_g[(n + 1) * kL + t];
        bt0 = bp_g[(n + 1) * kL + t];
      }
    }
    wg_barrier();  // b2: operands visible

    // ---- PA: KK (waves 0-3 -> strictly-lower A) / QK (waves 4-7 -> Aqk) ----
    float vv[2][4];
    {
      const int jmax = wave & 3;
      const short (*Asrc)[KST] = (wave < 4) ? sKn : sQn;
      f32x4 acc[4];
      acc[0] = 0; acc[1] = 0; acc[2] = 0; acc[3] = 0;
      if (wave >= 4) {  // issue v loads early; consumed at the Y epilogue
        #pragma unroll
        for (int vt = 0; vt < 2; ++vt)
          #pragma unroll
          for (int reg = 0; reg < 4; ++reg)
            vv[vt][reg] = vp_g[(size_t)(n * kL + iy0 + quad * 4 + reg) * kDv +
                               vt * 16 + n16];
      }
      #pragma unroll
      for (int ks = 0; ks < 4; ++ks) {
        short8 af = *(const short8*)&Asrc[iy0 + n16][ks * 32 + quad * 8];
        for (int jt = 0; jt <= jmax; ++jt) {
          short8 bf = *(const short8*)&sKn[jt * 16 + n16][ks * 32 + quad * 8];
          acc[jt] = MFMA16(af, bf, acc[jt]);
        }
      }
      if (wave < 4) {
        float sc[4];
        #pragma unroll
        for (int reg = 0; reg < 4; ++reg) {
          const int i = iy0 + quad * 4 + reg;
          sc[reg] = sBeta[cb][i] * sGi[cb][i];
        }
        for (int jt = 0; jt <= jmax; ++jt) {
          const int j = jt * 16 + n16;
          const float gej = sGe[cb][j];
          #pragma unroll
          for (int reg = 0; reg < 4; ++reg) {
            const int i = iy0 + quad * 4 + reg;
            if (j < i) sA[i][j] = sc[reg] * gej * acc[jt][reg];
          }
        }
      } else {
        float gi4[4];
        #pragma unroll
        for (int reg = 0; reg < 4; ++reg) gi4[reg] = sGi[cb][iy0 + quad * 4 + reg];
        for (int jt = 0; jt <= jmax; ++jt) {
          #pragma unroll
          for (int reg = 0; reg < 4; ++reg) {
            const int i = iy0 + quad * 4 + reg, j = jt * 16 + n16;
            sAqk[i][j] = (j <= i) ? f2bf(acc[jt][reg] * gi4[reg]) : (short)0;
          }
        }
      }
    }
    wg_barrier();  // b3

    // ---- interleaved: solve (waves 0-3, fp32) || PY = [kn;qn].S (waves 4-7) ----
    f32x4 yacc[2], oacc[2];
    auto py_step = [&](int ks) {
      short8 ak = *(const short8*)&sKn[iy0 + n16][ks * 32 + quad * 8];
      short8 aq = *(const short8*)&sQn[iy0 + n16][ks * 32 + quad * 8];
      #pragma unroll
      for (int vt = 0; vt < 2; ++vt) {
        short8 bs = *(const short8*)&sSb[vt * 16 + n16][ks * 32 + quad * 8];
        yacc[vt] = MFMA16(ak, bs, yacc[vt]);
        oacc[vt] = MFMA16(aq, bs, oacc[vt]);
      }
    };

    if (wave >= 4) {
      yacc[0] = 0; yacc[1] = 0; oacc[0] = 0; oacc[1] = 0;
      py_step(0);
    } else if (t < 64) {
      // S1: invert the four 16x16 unit-lower diagonal blocks
      const int I = t >> 4, c = t & 15;
      float x[16];
      #pragma unroll
      for (int i = 0; i < 16; ++i) {
        float xi = (i == c) ? 1.f : 0.f;
        for (int j = 0; j < i; ++j) xi -= sA[I * 16 + i][I * 16 + j] * x[j];
        x[i] = xi;
      }
      const float bc = sBeta[cb][I * 16 + c];
      #pragma unroll
      for (int i = 0; i < 16; ++i) {
        sVinv[I][i][c] = x[i];
        sTb[I * 16 + i][I * 16 + c] = f2bf(x[i] * bc);
      }
    }
    wg_barrier();  // b4

    if (wave >= 4) {
      py_step(1);
    } else {
      // S2a: M10 = V1*A10, M32 = V3*A32   (t < 256)
      const int r = t >> 4, c = t & 15;
      float m1 = 0.f, m3 = 0.f;
      #pragma unroll
      for (int kk = 0; kk < 16; ++kk) {
        m1 += sVinv[1][r][kk] * sA[16 + kk][c];
        m3 += sVinv[3][r][kk] * sA[48 + kk][32 + c];
      }
      sTmp[r][c] = m1;
      sTmp[16 + r][c] = m3;
    }
    wg_barrier();  // b5

    if (wave >= 4) {
      py_step(2);
    } else {
      // S2b: X10 = -M10*V0 ; X32 = -M32*V2
      const int r = t >> 4, c = t & 15;
      float x1 = 0.f, x3 = 0.f;
      #pragma unroll
      for (int kk = 0; kk < 16; ++kk) {
        x1 += sTmp[r][kk] * sVinv[0][kk][c];
        x3 += sTmp[16 + r][kk] * sVinv[2][kk][c];
      }
      x1 = -x1; x3 = -x3;
      sA[16 + r][c] = x1;
      sTb[16 + r][c] = f2bf(x1 * sBeta[cb][c]);
      sA[48 + r][32 + c] = x3;
      sTb[48 + r][32 + c] = f2bf(x3 * sBeta[cb][32 + c]);
    }
    wg_barrier();  // b6

    if (wave >= 4) {
      py_step(3);
    } else {
      // S3a: M = A_bl * W1inv  (32x32), W1inv = [[V0,0],[X10,V1]]
      #pragma unroll
      for (int p = 0; p < 4; ++p) {
        const int idx = t + 256 * p;
        const int r = idx >> 5, c = idx & 31;
        float m = 0.f;
        if (c < 16) {
          #pragma unroll
          for (int kk = 0; kk < 16; ++kk) m += sA[32 + r][kk] * sVinv[0][kk][c];
          #pragma unroll
          for (int kk = 16; kk < 32; ++kk) m += sA[32 + r][kk] * sA[kk][c];
        } else {
          #pragma unroll
          for (int kk = 16; kk < 32; ++kk)
            m += sA[32 + r][kk] * sVinv[1][kk - 16][c - 16];
        }
        sTmp[r][c] = m;
      }
    }
    wg_barrier();  // b7

    // ---- b7-b8: waves 4-7: Y epilogue -> sYT ; waves 0-3: S3b ----
    if (wave >= 4) {
      #pragma unroll
      for (int vt = 0; vt < 2; ++vt) {
        short4v yw;
        #pragma unroll
        for (int reg = 0; reg < 4; ++reg) {
          const float ge = sGe[cb][iy0 + quad * 4 + reg];
          yw[reg] = f2bf(ge * (vv[vt][reg] - yacc[vt][reg]));
          oacc[vt][reg] *= ge;
        }
        *(short4v*)&sYT[vt * 16 + n16][iy0 + quad * 4] = yw;
      }
    } else {
      // S3b: X_bl = -W2inv * M, W2inv = [[V2,0],[X32,V3]]
      #pragma unroll
      for (int p = 0; p < 4; ++p) {
        const int idx = t + 256 * p;
        const int r = idx >> 5, c = idx & 31;
        float xv = 0.f;
        if (r < 16) {
          #pragma unroll
          for (int kk = 0; kk < 16; ++kk) xv += sVinv[2][r][kk] * sTmp[kk][c];
        } else {
          #pragma unroll
          for (int kk = 0; kk < 16; ++kk) xv += sA[32 + r][32 + kk] * sTmp[kk][c];
          #pragma unroll
          for (int kk = 16; kk < 32; ++kk)
            xv += sVinv[3][r - 16][kk - 16] * sTmp[kk][c];
        }
        sTb[32 + r][c] = f2bf(-xv * sBeta[cb][c]);
      }
    }
    wg_barrier();  // b8

    // ---- PC: corg^T = gexp_i*(T.Y)^T (all 8 waves) ; + next-chunk norms/gates ----
    {
      const int ic0 = (wave >> 1) * 16, vc0 = (wave & 1) * 16;
      f32x4 cacc; cacc = 0;
      #pragma unroll
      for (int ks = 0; ks < 2; ++ks) {
        short8 af = *(const short8*)&sTb[ic0 + n16][ks * 32 + quad * 8];
        short8 bf = *(const short8*)&sYT[vc0 + n16][ks * 32 + quad * 8];
        cacc = MFMA16(af, bf, cacc);
      }
      short4v cw;
      #pragma unroll
      for (int reg = 0; reg < 4; ++reg)
        cw[reg] = f2bf(cacc[reg] * sGe[cb][ic0 + quad * 4 + reg]);
      *(short4v*)&sCT[vc0 + n16][ic0 + quad * 4] = cw;
    }
    if (n + 1 < kNC) {
      // norms for chunk n+1 (prefetched regs; loads have had the whole
      // solve chain to land - first vmcnt wait is here, at use)
      float ssk = 0.f, ssq = 0.f;
      #pragma unroll
      for (int m = 0; m < 4; ++m) {
        ssk += kv4[m].x * kv4[m].x + kv4[m].y * kv4[m].y +
               kv4[m].z * kv4[m].z + kv4[m].w * kv4[m].w;
        ssq += qv4[m].x * qv4[m].x + qv4[m].y * qv4[m].y +
               qv4[m].z * qv4[m].z + qv4[m].w * qv4[m].w;
      }
      #pragma unroll
      for (int off = 4; off >= 1; off >>= 1) {
        ssk += __shfl_xor(ssk, off, 8);
        ssq += __shfl_xor(ssq, off, 8);
      }
      krk = 1.f / (sqrtf(ssk) + kEps);
      krq = kScale / (sqrtf(ssq) + kEps);
      if (t < kL) {  // gate cumsum for chunk n+1 -> buffer cb^1
        float gv = gv0;
        #pragma unroll
        for (int off = 1; off < 64; off <<= 1) {
          float up = __shfl_up(gv, off, 64);
          if (lane >= off) gv += up;
        }
        sGe[cb ^ 1][t] = __expf(gv);
        sGi[cb ^ 1][t] = __expf(-gv);
        sBeta[cb ^ 1][t] = bt0;
      }
    }
    wg_barrier();  // b9

    // ---- PO (waves 4-7): O = gexp*qn.S + Aqk2.corg -> global
    // ---- PSU (waves 0-3): S = decay*S + kn^T.corg (in accumulators) ----
    if (wave >= 4) {
      const int io = (wave & 3) * 16;
      #pragma unroll
      for (int ks = 0; ks < 2; ++ks) {
        short8 af = *(const short8*)&sAqk[io + n16][ks * 32 + quad * 8];
        #pragma unroll
        for (int vt = 0; vt < 2; ++vt) {
          short8 bf = *(const short8*)&sCT[vt * 16 + n16][ks * 32 + quad * 8];
          oacc[vt] = MFMA16(af, bf, oacc[vt]);
        }
      }
      // O stores fly; no barrier ever waits on their ack (raw barriers)
      #pragma unroll
      for (int vt = 0; vt < 2; ++vt)
        #pragma unroll
        for (int reg = 0; reg < 4; ++reg)
          op_g[(size_t)(n * kL + io + quad * 4 + reg) * kDv + vt * 16 + n16] =
              oacc[vt][reg];
    } else {
      const float decay = sGe[cb][kL - 1];
      Sacc[0] *= decay; Sacc[1] *= decay; Sacc[2] *= decay; Sacc[3] *= decay;
      #pragma unroll
      for (int a = 0; a < 2; ++a) {
        const int d0 = (wave & 3) * 32 + a * 16;
        #pragma unroll
        for (int ks = 0; ks < 2; ++ks) {
          short8 af;
          #pragma unroll
          for (int j = 0; j < 8; ++j) af[j] = sKn[ks * 32 + quad * 8 + j][d0 + n16];
          #pragma unroll
          for (int b = 0; b < 2; ++b) {
            short8 bf = *(const short8*)&sCT[b * 16 + n16][ks * 32 + quad * 8];
            Sacc[a * 2 + b] = MFMA16(af, bf, Sacc[a * 2 + b]);
          }
        }
        #pragma unroll
        for (int b = 0; b < 2; ++b) {
          short4v sw;
          #pragma unroll
          for (int reg = 0; reg < 4; ++reg) sw[reg] = f2bf(Sacc[a * 2 + b][reg]);
          *(short4v*)&sSb[b * 16 + n16][d0 + quad * 4] = sw;
        }
      }
    }
  }

  // ---- final state (fp32 from accumulators) -> d_out tail ----
  if (wave < 4) {
    #pragma unroll
    for (int a = 0; a < 2; ++a)
      #pragma unroll
      for (int b = 0; b < 2; ++b)
        #pragma unroll
        for (int reg = 0; reg < 4; ++reg) {
          const int d = (wave & 3) * 32 + a * 16 + quad * 4 + reg;
          sp_g[(size_t)d * kDv + b * 16 + n16] = Sacc[a * 2 + b][reg];
        }
  }
}

}  // namespace

extern "C" void kernel_launch(void* const* d_in, const int* in_sizes, int n_in,
                              void* d_out, int out_size, void* d_ws, size_t ws_size,
                              hipStream_t stream) {
  (void)in_sizes; (void)n_in; (void)d_ws; (void)ws_size; (void)out_size;
  const float* q    = (const float*)d_in[0];
  const float* k    = (const float*)d_in[1];
  const float* v    = (const float*)d_in[2];
  const float* g    = (const float*)d_in[3];
  const float* beta = (const float*)d_in[4];
  float* out = (float*)d_out;
  gdn_mfma_kernel<<<dim3(kBH * (kDv / 32)), dim3(kThreads), 0, stream>>>(
      q, k, v, g, beta, out);
}